// Round 13
// baseline (141.726 us; speedup 1.0000x reference)
//
#include <hip/hip_runtime.h>

typedef unsigned short ushort;
typedef unsigned int uint;

constexpr int B = 2, C = 64, H = 112, W = 112;
constexpr int HW = H * W;          // 12544
constexpr int NPIX = B * HW;       // 25088
constexpr int NBLK = 512;          // 2 images x 16x16 tiles of 7x7 -> exactly 2 blocks/CU
constexpr float EPS_LN = 1e-6f, EPS_NORM = 1e-7f;

typedef __attribute__((ext_vector_type(8))) short bf16x8;   // 8 bf16 = 4 VGPRs
typedef __attribute__((ext_vector_type(4))) float f32x4;

__device__ __forceinline__ float rcp_fast(float x) { return __builtin_amdgcn_rcpf(x); }
__device__ __forceinline__ float sigmoid_f(float x) { return rcp_fast(1.f + __expf(-x)); }
__device__ __forceinline__ int uni(int x) { return __builtin_amdgcn_readfirstlane(x); }
__device__ __forceinline__ int div7s(int x)  { return (x * 9363) >> 16; }   // exact for 0<=x<64
__device__ __forceinline__ int div13s(int x) { return (x * 5042) >> 16; }   // exact for 0<=x<169

// f32 -> bf16 bits (round-nearest-even) + pair pack/unpack.
__device__ __forceinline__ ushort rne16(float x) {
    uint u = __float_as_uint(x);
    u += 0x7fffu + ((u >> 16) & 1u);
    return (ushort)(u >> 16);
}
__device__ __forceinline__ uint pack2(float a, float b) {
    return (uint)rne16(a) | ((uint)rne16(b) << 16);
}
__device__ __forceinline__ float2 up2(uint u) {
    return make_float2(__uint_as_float(u << 16), __uint_as_float(u & 0xffff0000u));
}
__device__ __forceinline__ float up1(ushort u) {
    return __uint_as_float((uint)u << 16);
}

__device__ __forceinline__ f32x4 mfma16(bf16x8 a, bf16x8 b, f32x4 c) {
    return __builtin_amdgcn_mfma_f32_16x16x32_bf16(a, b, c, 0, 0, 0);
}

// XCD-patch swizzle (BOTH kernels -> producer/consumer share an XCD L2).
__device__ __forceinline__ void decode_blk(int blk, int& b, int& ty, int& tx) {
    int p8 = blk & 7, i = blk >> 3;          // i in [0,64)
    b = p8 >> 2;
    int quad = p8 & 3;
    int lty = i >> 3, ltx = i & 7;           // 8x8 tiles per quadrant
    ty = (quad >> 1) * 8 + lty;              // [0,16)
    tx = (quad & 1) * 8 + ltx;
}

// ---------------------------------------------------------------------------
// Split-bf16 GEMM helpers. Weights/activations [64 rows][72] bf16 hi/lo.
// T14 async-split staging: wload* (global->reg, issue EARLY) + wstore*
// (reg->LDS, write LATE) — identical values to the fused stage_w/stage_wpad.
// ---------------------------------------------------------------------------
__device__ __forceinline__ void stage_w(const float* __restrict__ wsrc,
                                        ushort* wh, ushort* wl, int tid)
{
#pragma unroll
    for (int i = 0; i < 8; ++i) {
        int idx2 = i * 256 + tid;            // 2048 float pairs = 64x64
        int o = idx2 >> 5, k = (idx2 & 31) * 2;
        float2 xy = *(const float2*)&wsrc[o * 64 + k];
        uint h = pack2(xy.x, xy.y);
        *(uint*)&wh[o * 72 + k] = h;
        *(uint*)&wl[o * 72 + k] = pack2(xy.x - __uint_as_float((h & 0xffffu) << 16),
                                        xy.y - __uint_as_float(h & 0xffff0000u));
    }
}

__device__ __forceinline__ void wload64(const float* __restrict__ wsrc, int tid, float* r) {
#pragma unroll
    for (int i = 0; i < 8; ++i) {
        int idx2 = i * 256 + tid;
        int o = idx2 >> 5, k = (idx2 & 31) * 2;
        float2 xy = *(const float2*)&wsrc[o * 64 + k];
        r[2 * i] = xy.x; r[2 * i + 1] = xy.y;
    }
}
__device__ __forceinline__ void wstore64(const float* r, ushort* wh, ushort* wl, int tid) {
#pragma unroll
    for (int i = 0; i < 8; ++i) {
        int idx2 = i * 256 + tid;
        int o = idx2 >> 5, k = (idx2 & 31) * 2;
        uint h = pack2(r[2 * i], r[2 * i + 1]);
        *(uint*)&wh[o * 72 + k] = h;
        *(uint*)&wl[o * 72 + k] = pack2(r[2 * i]     - __uint_as_float((h & 0xffffu) << 16),
                                        r[2 * i + 1] - __uint_as_float(h & 0xffff0000u));
    }
}

// padded nrow x ncol (<=64x64) matrix, arbitrary row stride; thread t: row
// t>>2, col quarter t&3 (identical mapping/values to old stage_wpad).
__device__ __forceinline__ void wloadpad(const float* __restrict__ src, int ld,
                                         int nrow, int ncol, int tid, float* r)
{
    const int o = tid >> 2, q = (tid & 3) * 16;
#pragma unroll
    for (int jj = 0; jj < 8; ++jj) {
        int c = q + 2 * jj;
        r[2 * jj]     = (o < nrow && c < ncol)     ? src[o * ld + c]     : 0.f;
        r[2 * jj + 1] = (o < nrow && c + 1 < ncol) ? src[o * ld + c + 1] : 0.f;
    }
}
__device__ __forceinline__ void wstorepad(const float* r, ushort* wh, ushort* wl, int tid)
{
    const int o = tid >> 2, q = (tid & 3) * 16;
#pragma unroll
    for (int jj = 0; jj < 8; ++jj) {
        int c = q + 2 * jj;
        uint hh = pack2(r[2 * jj], r[2 * jj + 1]);
        uint ll = pack2(r[2 * jj]     - __uint_as_float((hh & 0xffffu) << 16),
                        r[2 * jj + 1] - __uint_as_float(hh & 0xffff0000u));
        *(uint*)&wh[o * 72 + c] = hh;
        *(uint*)&wl[o * 72 + c] = ll;
    }
}

__device__ __forceinline__ void gemm64_acc(const ushort* __restrict__ wh, const ushort* __restrict__ wl,
                                           const ushort* __restrict__ xh, const ushort* __restrict__ xl,
                                           int lm, int l4, int pp, f32x4 acc[4])
{
#pragma unroll
    for (int kt = 0; kt < 2; ++kt) {
        const int xo = pp * 72 + kt * 32 + l4 * 8;
        bf16x8 bh = *(const bf16x8*)&xh[xo];
        bf16x8 bl = *(const bf16x8*)&xl[xo];
#pragma unroll
        for (int mt = 0; mt < 4; ++mt) {
            const int wo = (mt * 16 + lm) * 72 + kt * 32 + l4 * 8;
            bf16x8 ah = *(const bf16x8*)&wh[wo];
            bf16x8 al = *(const bf16x8*)&wl[wo];
            acc[mt] = mfma16(al, bh, acc[mt]);
            acc[mt] = mfma16(ah, bl, acc[mt]);
            acc[mt] = mfma16(ah, bh, acc[mt]);
        }
    }
}

__device__ __forceinline__ void gemm64(const ushort* __restrict__ wh, const ushort* __restrict__ wl,
                                       const ushort* __restrict__ xh, const ushort* __restrict__ xl,
                                       const float* __restrict__ bias,
                                       int lm, int l4, int pp, f32x4 acc[4])
{
#pragma unroll
    for (int mt = 0; mt < 4; ++mt) {
        const int ob = mt * 16 + l4 * 4;
        acc[mt][0] = bias[ob]; acc[mt][1] = bias[ob + 1];
        acc[mt][2] = bias[ob + 2]; acc[mt][3] = bias[ob + 3];
    }
    gemm64_acc(wh, wl, xh, xl, lm, l4, pp, acc);
}

// ---------------------------------------------------------------------------
// k1: px = range_proj(semantic) -> px16[p][64] (bf16) + sqnorm[p].
// Unchanged from r7 (full split-bf16 MFMA; verified; ~7 us).
// ---------------------------------------------------------------------------
__global__ __launch_bounds__(256) void k1_range_proj(
    const float* __restrict__ sem,
    const float* __restrict__ w1, const float* __restrict__ b1,
    const float* __restrict__ g,  const float* __restrict__ be,
    const float* __restrict__ w2, const float* __restrict__ b2,
    ushort* __restrict__ px16, float* __restrict__ sqnorm)
{
    __shared__ __align__(16) ushort u16[28160];   // 56320 B
    ushort* wh1 = u16;                 // [64][72] each (4608 ushorts)
    ushort* wl1 = u16 + 4608;
    ushort* wh2 = u16 + 9216;
    ushort* wl2 = u16 + 13824;
    ushort* xh  = u16 + 18432;         // activations / s (reused)
    ushort* xl  = u16 + 23040;         // ..27648
    float*  bv  = (float*)(u16 + 27648);   // b1|g|be|b2 (256 floats)

    const int tid = threadIdx.x, lane = tid & 63, wv = tid >> 6;
    const int lm = lane & 15, l4 = lane >> 4;
    int b, ty, tx; decode_blk(blockIdx.x, b, ty, tx);

    {
        const int lp = lane < 49 ? lane : 48;
        const int py = div7s(lp), px = lp - py * 7;
        const int hw = (ty * 7 + py) * W + tx * 7 + px;
        const bool a = lane < 49;
        float xv[16];
#pragma unroll
        for (int j = 0; j < 16; ++j)
            xv[j] = a ? sem[(size_t)(b * 64 + wv * 16 + j) * HW + hw] : 0.f;
        uint hu[8], lu[8];
#pragma unroll
        for (int jj = 0; jj < 8; ++jj) {
            uint hh = pack2(xv[2 * jj], xv[2 * jj + 1]);
            hu[jj] = hh;
            lu[jj] = pack2(xv[2 * jj]     - __uint_as_float((hh & 0xffffu) << 16),
                           xv[2 * jj + 1] - __uint_as_float(hh & 0xffff0000u));
        }
        const int rb = lane * 72 + wv * 16;
        *(uint4*)&xh[rb]     = make_uint4(hu[0], hu[1], hu[2], hu[3]);
        *(uint4*)&xh[rb + 8] = make_uint4(hu[4], hu[5], hu[6], hu[7]);
        *(uint4*)&xl[rb]     = make_uint4(lu[0], lu[1], lu[2], lu[3]);
        *(uint4*)&xl[rb + 8] = make_uint4(lu[4], lu[5], lu[6], lu[7]);
    }
    stage_w(w1, wh1, wl1, tid);
    stage_w(w2, wh2, wl2, tid);
    if (tid < 64) { bv[tid] = b1[tid]; bv[64 + tid] = g[tid];
                    bv[128 + tid] = be[tid]; bv[192 + tid] = b2[tid]; }
    __syncthreads();

    const int pp = wv * 16 + lm;
    f32x4 f[4];
    gemm64(wh1, wl1, xh, xl, bv, lm, l4, pp, f);

    float psum = 0.f, psq = 0.f;
#pragma unroll
    for (int mt = 0; mt < 4; ++mt)
#pragma unroll
        for (int r = 0; r < 4; ++r) { float fv = f[mt][r]; psum += fv; psq += fv * fv; }
    psum += __shfl_xor(psum, 16); psum += __shfl_xor(psum, 32);
    psq  += __shfl_xor(psq, 16);  psq  += __shfl_xor(psq, 32);
    const float m = psum * (1.f / 64.f);
    const float rstd = rsqrtf(psq * (1.f / 64.f) - m * m + EPS_LN);

    float sv_[16];
#pragma unroll
    for (int mt = 0; mt < 4; ++mt)
#pragma unroll
        for (int r = 0; r < 4; ++r) {
            const int o = mt * 16 + l4 * 4 + r;
            float y = bv[64 + o] * (f[mt][r] - m) * rstd + bv[128 + o];
            sv_[mt * 4 + r] = y * sigmoid_f(y);
        }
    __syncthreads();
#pragma unroll
    for (int mt = 0; mt < 4; ++mt) {
        uint h0 = pack2(sv_[4 * mt],     sv_[4 * mt + 1]);
        uint h1 = pack2(sv_[4 * mt + 2], sv_[4 * mt + 3]);
        uint l0 = pack2(sv_[4 * mt]     - __uint_as_float((h0 & 0xffffu) << 16),
                        sv_[4 * mt + 1] - __uint_as_float(h0 & 0xffff0000u));
        uint l1 = pack2(sv_[4 * mt + 2] - __uint_as_float((h1 & 0xffffu) << 16),
                        sv_[4 * mt + 3] - __uint_as_float(h1 & 0xffff0000u));
        const int so = pp * 72 + mt * 16 + l4 * 4;
        *(uint2*)&xh[so] = make_uint2(h0, h1);
        *(uint2*)&xl[so] = make_uint2(l0, l1);
    }
    __syncthreads();

    f32x4 z[4];
    gemm64(wh2, wl2, xh, xl, bv + 192, lm, l4, pp, z);

    float sq = 0.f;
#pragma unroll
    for (int mt = 0; mt < 4; ++mt)
#pragma unroll
        for (int r = 0; r < 4; ++r) sq += z[mt][r] * z[mt][r];
    sq += __shfl_xor(sq, 16); sq += __shfl_xor(sq, 32);

    if (pp < 49) {
        const int py = div7s(pp), px = pp - py * 7;
        const int hwi = (ty * 7 + py) * W + tx * 7 + px;
        ushort* dst = &px16[((size_t)b * HW + hwi) * 64];
#pragma unroll
        for (int mt = 0; mt < 4; ++mt)
            *(uint2*)&dst[mt * 16 + l4 * 4] =
                make_uint2(pack2(z[mt][0], z[mt][1]), pack2(z[mt][2], z[mt][3]));
        if (l4 == 0) sqnorm[(size_t)b * HW + hwi] = sq;
    }
}

// ---------------------------------------------------------------------------
// k23 (r13): r12 + T14 async-split weight staging. A1 loads at entry; A2
// loads before gemm1; A3 loads before gemm_acc; op_w2 loads at P6a — each
// ds_write happens late, so the global-load latency hides under the
// intervening compute phase instead of sitting exposed between barriers.
// Values and layouts identical to r12 (pure load reordering).
// ---------------------------------------------------------------------------
__global__ __launch_bounds__(256, 2) void k23_fused(
    const ushort* __restrict__ px16, const float* __restrict__ sqnorm,
    const float* __restrict__ sem,  const float* __restrict__ spat,
    const float* __restrict__ fw1, const float* __restrict__ fb1,
    const float* __restrict__ fg,  const float* __restrict__ fbe,
    const float* __restrict__ fw2, const float* __restrict__ fb2,
    const float* __restrict__ w1, const float* __restrict__ b1,
    const float* __restrict__ g,  const float* __restrict__ be,
    const float* __restrict__ w2, const float* __restrict__ b2,
    const float* __restrict__ sigma_, float* __restrict__ out)
{
    __shared__ __align__(16) float smem[18048];          // 72192 B arena
    // Phase A:
    ushort* haloA  = (ushort*)smem;                      // [169][64] bf16 fl [0,5408)
    ushort* dmat16 = (ushort*)(smem + 5408);             // [176][66] bf16 fl [5408,11216)
    float*  sqn_l  = smem + 11216;                       // 169 fl [11216,11385)
    ushort* haloB  = (ushort*)(smem + 12640);            // [169][64] bf16 fl [12640,18048) — staged at ENTRY
    // post-extraction overlays (haloA/dmat16/sqn dead):
    float*  comb  = smem;                                // 3136 fl [0,3136)
    float*  bv3   = smem + 3136;                         // 256: fb1|fb2|fg|fbe
    float*  pt    = smem + 3136;                         // 64 (overlays dead fb1)
    ushort* Xh    = (ushort*)(smem + 3392);              // [64][72] fl [3392,5696)
    ushort* Xl    = (ushort*)(smem + 5696);              // fl [5696,8000)
    ushort* Ah    = (ushort*)(smem + 8000);              // fl [8000,10304)
    ushort* Al    = (ushort*)(smem + 10304);             // fl [10304,12608)
    // P5/P6 overlays:
    float*  bvP   = smem + 3136;                         // 256 (pt/bv3 dead)
    ushort* whiP  = (ushort*)(smem + 8000);              // over A strip
    ushort* wloP  = (ushort*)(smem + 10304);
    ushort* ahiP  = (ushort*)(smem + 3392);              // over X strip
    ushort* aloP  = (ushort*)(smem + 5696);

    const int tid = threadIdx.x, lane = tid & 63, wv = tid >> 6;
    const int lm = lane & 15, l4 = lane >> 4;
    int b, ty, tx; decode_blk(blockIdx.x, b, ty, tx);
    const int lp  = lane < 49 ? lane : 48;
    const int py  = div7s(lp), pxl = lp - py * 7;
    const int h = ty * 7 + py, w = tx * 7 + pxl;
    const int hw = h * W + w;
    const int h0 = ty * 7 - 3, w0 = tx * 7 - 3;
    const bool act = lane < 49;
    const int pp = wv * 16 + lm;

    // ---- sv16 prefetch: this thread's 16-channel slice (X2 staging) ----
    float sv16[16];
#pragma unroll
    for (int j = 0; j < 16; ++j)
        sv16[j] = sem[(size_t)(b * 64 + wv * 16 + j) * HW + hw];

    // ---- A1 async-load at ENTRY (consumed post-extraction) ----
    float fa1[16];
    wloadpad(fw1, 113, 49, 49, tid, fa1);

    // ---- haloB staging at ENTRY: latency hides under P1+P2+extraction ----
    if (tid < 169) {
        const int ry = div13s(tid), rx = tid - ry * 13;
        const int hh = h0 + ry, ww = w0 + rx;
        const bool valid = (unsigned)hh < (unsigned)H && (unsigned)ww < (unsigned)W;
        const int soff = hh * W + ww;
        const int rsw = (tid & 7), rb_ = tid << 6;
#pragma unroll
        for (int cq = 0; cq < 8; ++cq) {
            uint4 v = make_uint4(0u, 0u, 0u, 0u);
            if (valid) {
                const float* sp = &spat[(size_t)(b * 64 + 8 * cq) * HW + soff];
                v.x = pack2(sp[0],      sp[HW]);
                v.y = pack2(sp[2 * HW], sp[3 * HW]);
                v.z = pack2(sp[4 * HW], sp[5 * HW]);
                v.w = pack2(sp[6 * HW], sp[7 * HW]);
            }
            *(uint4*)&haloB[rb_ + ((cq ^ rsw) << 3)] = v;
        }
    }

    // ---- P1: stage px halo -> haloA (bf16): 1352 16-B loads ----
    for (int i = 0; i < 6; ++i) {
        int idx = i * 256 + tid;
        if (idx < 1352) {
            int r = idx >> 3, q = idx & 7;
            int ry = div13s(r), rx = r - ry * 13;
            int hh = h0 + ry, ww = w0 + rx;
            bool valid = (unsigned)hh < (unsigned)H && (unsigned)ww < (unsigned)W;
            uint4 v = make_uint4(0u, 0u, 0u, 0u);
            if (valid) v = *(const uint4*)&px16[((size_t)b * HW + hh * W + ww) * 64 + 8 * q];
            *(uint4*)&haloA[(r << 6) + ((q ^ (r & 7)) << 3)] = v;
        }
    }
    if (tid < 169) {
        int ry = div13s(tid), rx = tid - ry * 13;
        int hh = h0 + ry, ww = w0 + rx;
        bool valid = (unsigned)hh < (unsigned)H && (unsigned)ww < (unsigned)W;
        float v = 0.f;
        if (valid) v = sqnorm[(size_t)b * HW + hh * W + ww];
        sqn_l[tid] = v;
    }
    __syncthreads();

    // ---- P2-MFMA: D[hp][p] = <haloA[hp], haloA[rp(p)]> -> dmat16 (bf16) ----
    {
        const int qp = pp < 49 ? pp : 48;
        const int pyp = div7s(qp), pxp = qp - pyp * 7;
        const int rpp = pyp * 13 + pxp + 42;
        bf16x8 bc0 = *(const bf16x8*)&haloA[(rpp << 6) + ((l4 ^ (rpp & 7)) << 3)];
        bf16x8 bc1 = *(const bf16x8*)&haloA[(rpp << 6) + (((4 + l4) ^ (rpp & 7)) << 3)];
#pragma unroll
        for (int mt = 0; mt < 11; ++mt) {
            const int r = mt * 16 + lm;
            bf16x8 a0 = *(const bf16x8*)&haloA[(r << 6) + ((l4 ^ (r & 7)) << 3)];
            bf16x8 a1 = *(const bf16x8*)&haloA[(r << 6) + (((4 + l4) ^ (r & 7)) << 3)];
            f32x4 d = {0.f, 0.f, 0.f, 0.f};
            d = mfma16(a0, bc0, d);
            d = mfma16(a1, bc1, d);
            const int orow = mt * 16 + l4 * 4;
#pragma unroll
            for (int rr = 0; rr < 4; ++rr)
                dmat16[(orow + rr) * 66 + pp] = rne16(d[rr]);
        }
    }
    __syncthreads();

    // ---- extraction (wave-split n) into regs ----
    const int rbase = py * 13 + pxl;
    const int rp = rbase + 42;
    float cbl[13];
    {
        const float sqc = sqn_l[rp];
        const float sg_ = sigma_[0];
        const float inv2s2 = rcp_fast(2.f * sg_ * sg_);
#pragma unroll
        for (int i = 0; i < 13; ++i) {
            const int n = uni(wv + 4 * i);
            cbl[i] = 0.f;
            if (n < 49) {
                int ryn = div7s(n), rxn = n - ryn * 7;
                int dy = ryn - 3, dx = rxn - 3;
                int rn = rbase + ryn * 13 + rxn;
                float dot = up1(dmat16[rn * 66 + lane]);
                float dist2 = fmaxf(sqn_l[rn] + sqc - 2.f * dot, 0.f);
                bool validn = (unsigned)(h + dy) < (unsigned)H && (unsigned)(w + dx) < (unsigned)W;
                float d2n = (float)(dy * dy + dx * dx);
                cbl[i] = validn ? __expf(-(dist2 * (1.f / 128.f) + d2n * inv2s2)) : 0.f;
            }
        }
    }
    __syncthreads();   // dmat16/haloA/sqn dead below

    // ---- post-extraction: comb f32 + X1(comb bf16) + A1 store + bv3;
    //      A2 async-load issues here (consumed after gemm1) ----
    float fa2[16];
    wloadpad(fw1 + 49, 113, 49, 64, tid, fa2);
#pragma unroll
    for (int i = 0; i < 13; ++i) {
        const int n = wv + 4 * i;
        if (n < 49) {
            float v = cbl[i];
            comb[n * 64 + lane] = v;
            ushort hh = rne16(v);
            Xh[lane * 72 + n] = hh;
            Xl[lane * 72 + n] = rne16(v - up1(hh));
        }
    }
    if (tid < 64) {
#pragma unroll
        for (int r = 49; r < 64; ++r) { Xh[tid * 72 + r] = 0; Xl[tid * 72 + r] = 0; }
        bv3[tid]       = (tid < 49) ? fb1[tid] : 0.f;
        bv3[64 + tid]  = (tid < 49) ? fb2[tid] : 0.f;
        bv3[128 + tid] = (tid < 49) ? fg[tid]  : 0.f;
        bv3[192 + tid] = (tid < 49) ? fbe[tid] : 0.f;
    }
    wstorepad(fa1, Ah, Al, tid);   // A1 = comb-half of fx_w1 (loaded at entry)
    __syncthreads();

    // ---- P3-MFMA: conv1 = A1*X1 + A2*X2, conv2 = A3*X3 ----
    f32x4 accF[4];
    gemm64(Ah, Al, Xh, Xl, bv3, lm, l4, pp, accF);   // bias fb1 + comb part
    __syncthreads();                                  // A1/X1 reads done

    // X2 = sem (from sv16); A2 store (loaded pre-gemm1); A3 async-load
    float fa3[16];
    wloadpad(fw2, 49, 49, 49, tid, fa3);
    {
        uint hu[8], lu[8];
#pragma unroll
        for (int jj = 0; jj < 8; ++jj) {
            float x0 = sv16[2 * jj], x1 = sv16[2 * jj + 1];
            uint hh = pack2(x0, x1);
            hu[jj] = hh;
            lu[jj] = pack2(x0 - __uint_as_float((hh & 0xffffu) << 16),
                           x1 - __uint_as_float(hh & 0xffff0000u));
        }
        const int rb = lane * 72 + wv * 16;
        *(uint4*)&Xh[rb]     = make_uint4(hu[0], hu[1], hu[2], hu[3]);
        *(uint4*)&Xh[rb + 8] = make_uint4(hu[4], hu[5], hu[6], hu[7]);
        *(uint4*)&Xl[rb]     = make_uint4(lu[0], lu[1], lu[2], lu[3]);
        *(uint4*)&Xl[rb + 8] = make_uint4(lu[4], lu[5], lu[6], lu[7]);
    }
    wstorepad(fa2, Ah, Al, tid);
    __syncthreads();

    gemm64_acc(Ah, Al, Xh, Xl, lm, l4, pp, accF);    // += sem part

    // LN over o<49 (shfl across l4-groups) + SiLU -> s in regs
    float sarr[16];
    {
        float psum = 0.f, psq = 0.f;
#pragma unroll
        for (int mt = 0; mt < 4; ++mt)
#pragma unroll
            for (int r = 0; r < 4; ++r) {
                const int o = mt * 16 + l4 * 4 + r;
                if (o < 49) { float fv = accF[mt][r]; psum += fv; psq += fv * fv; }
            }
        psum += __shfl_xor(psum, 16); psum += __shfl_xor(psum, 32);
        psq  += __shfl_xor(psq, 16);  psq  += __shfl_xor(psq, 32);
        const float m = psum * (1.f / 49.f);
        const float rstd = rsqrtf(psq * (1.f / 49.f) - m * m + EPS_LN);
#pragma unroll
        for (int mt = 0; mt < 4; ++mt)
#pragma unroll
            for (int r = 0; r < 4; ++r) {
                const int o = mt * 16 + l4 * 4 + r;
                float s = 0.f;
                if (o < 49) {
                    float y = bv3[128 + o] * (accF[mt][r] - m) * rstd + bv3[192 + o];
                    s = y * sigmoid_f(y);
                }
                sarr[mt * 4 + r] = s;
            }
    }
    __syncthreads();                                  // A2/X2 reads done

    // X3 = s (rows o, col pp); A3 store (loaded pre-gemm_acc)
#pragma unroll
    for (int mt = 0; mt < 4; ++mt) {
        uint h0_ = pack2(sarr[4 * mt],     sarr[4 * mt + 1]);
        uint h1_ = pack2(sarr[4 * mt + 2], sarr[4 * mt + 3]);
        uint l0_ = pack2(sarr[4 * mt]     - __uint_as_float((h0_ & 0xffffu) << 16),
                         sarr[4 * mt + 1] - __uint_as_float(h0_ & 0xffff0000u));
        uint l1_ = pack2(sarr[4 * mt + 2] - __uint_as_float((h1_ & 0xffffu) << 16),
                         sarr[4 * mt + 3] - __uint_as_float(h1_ & 0xffff0000u));
        const int so = pp * 72 + mt * 16 + l4 * 4;
        *(uint2*)&Xh[so] = make_uint2(h0_, h1_);
        *(uint2*)&Xl[so] = make_uint2(l0_, l1_);
    }
    wstorepad(fa3, Ah, Al, tid);
    __syncthreads();

    f32x4 accG[4];
    gemm64(Ah, Al, Xh, Xl, bv3 + 64, lm, l4, pp, accG);   // bias fb2

    // gate + comb update + column sums -> pt[pp]
    {
        float tacc = 0.f;
#pragma unroll
        for (int mt = 0; mt < 4; ++mt)
#pragma unroll
            for (int r = 0; r < 4; ++r) {
                const int o = mt * 16 + l4 * 4 + r;
                if (o < 49) {
                    float gate = 1.f + sigmoid_f(accG[mt][r]);
                    float cx = comb[o * 64 + pp] * gate;   // unique (o,pp) per lane
                    comb[o * 64 + pp] = cx;
                    tacc += cx;
                }
            }
        tacc += __shfl_xor(tacc, 16); tacc += __shfl_xor(tacc, 32);
        if (l4 == 0) pt[pp] = tacc;
    }
    __syncthreads();
    const float inv = rcp_fast(pt[lane] + EPS_NORM);
    __syncthreads();   // all pt reads done -> bvP overlay safe

    // ---- stage op_w1 (over dead A strip) + bias vec; hides under P5 ----
    stage_w(w1, whiP, wloP, tid);
    if (tid < 64) { bvP[tid] = b1[tid]; bvP[64 + tid] = g[tid];
                    bvP[128 + tid] = be[tid]; bvP[192 + tid] = b2[tid]; }

    // ---- P5: weighted neighborhood reduction (haloB, staged at entry) ----
    const int c0 = uni(wv * 16);
    const int qq0 = c0 >> 3;
    float acc[16];
#pragma unroll
    for (int j = 0; j < 16; ++j) acc[j] = 0.f;
    for (int ryn = 0; ryn < 7; ++ryn) {
#pragma unroll
        for (int rxn = 0; rxn < 7; ++rxn) {
            const int n = ryn * 7 + rxn;
            const int rn = rbase + ryn * 13 + rxn;
            float cn = comb[n * 64 + lane] * inv;
            const int rb_ = rn << 6, rsw = rn & 7;
#pragma unroll
            for (int q = 0; q < 2; ++q) {
                uint4 v = *(const uint4*)&haloB[rb_ + (((qq0 + q) ^ rsw) << 3)];
                float2 a = up2(v.x), bb = up2(v.y), c = up2(v.z), d = up2(v.w);
                acc[8 * q + 0] += cn * a.x;  acc[8 * q + 1] += cn * a.y;
                acc[8 * q + 2] += cn * bb.x; acc[8 * q + 3] += cn * bb.y;
                acc[8 * q + 4] += cn * c.x;  acc[8 * q + 5] += cn * c.y;
                acc[8 * q + 6] += cn * d.x;  acc[8 * q + 7] += cn * d.y;
            }
        }
    }
    __syncthreads();   // comb/haloB reads done; whiP/bvP staging visible

    // ---- P6a: write P5 result as split-bf16 activations [pixel][72];
    //      op_w2 async-load issues here (consumed at P6c) ----
    float fo2[16];
    wload64(w2, tid, fo2);
    {
        uint hu[8], lu[8];
#pragma unroll
        for (int jj = 0; jj < 8; ++jj) {
            float x0 = act ? acc[2 * jj] : 0.f;
            float x1 = act ? acc[2 * jj + 1] : 0.f;
            uint hh = pack2(x0, x1);
            hu[jj] = hh;
            lu[jj] = pack2(x0 - __uint_as_float((hh & 0xffffu) << 16),
                           x1 - __uint_as_float(hh & 0xffff0000u));
        }
        const int rb = lane * 72 + c0;
        *(uint4*)&ahiP[rb]     = make_uint4(hu[0], hu[1], hu[2], hu[3]);
        *(uint4*)&ahiP[rb + 8] = make_uint4(hu[4], hu[5], hu[6], hu[7]);
        *(uint4*)&aloP[rb]     = make_uint4(lu[0], lu[1], lu[2], lu[3]);
        *(uint4*)&aloP[rb + 8] = make_uint4(lu[4], lu[5], lu[6], lu[7]);
    }
    __syncthreads();

    // ---- P6b: conv1 MFMA + LN(shfl) ----
    f32x4 f6[4];
    gemm64(whiP, wloP, ahiP, aloP, bvP, lm, l4, pp, f6);

    float psum = 0.f, psq = 0.f;
#pragma unroll
    for (int mt = 0; mt < 4; ++mt)
#pragma unroll
        for (int r = 0; r < 4; ++r) { float fv = f6[mt][r]; psum += fv; psq += fv * fv; }
    psum += __shfl_xor(psum, 16); psum += __shfl_xor(psum, 32);
    psq  += __shfl_xor(psq, 16);  psq  += __shfl_xor(psq, 32);
    const float m6 = psum * (1.f / 64.f);
    const float rstd6 = rsqrtf(psq * (1.f / 64.f) - m6 * m6 + EPS_LN);

    float yv[16];
#pragma unroll
    for (int mt = 0; mt < 4; ++mt)
#pragma unroll
        for (int r = 0; r < 4; ++r) {
            const int o = mt * 16 + l4 * 4 + r;
            yv[mt * 4 + r] = bvP[64 + o] * (f6[mt][r] - m6) * rstd6 + bvP[128 + o];
        }
    __syncthreads();   // conv1 fragment reads done -> strips reusable

    // write y (split bf16) over act strip; op_w2 store (loaded at P6a)
#pragma unroll
    for (int mt = 0; mt < 4; ++mt) {
        uint h0_ = pack2(yv[4 * mt],     yv[4 * mt + 1]);
        uint h1_ = pack2(yv[4 * mt + 2], yv[4 * mt + 3]);
        uint l0_ = pack2(yv[4 * mt]     - __uint_as_float((h0_ & 0xffffu) << 16),
                         yv[4 * mt + 1] - __uint_as_float(h0_ & 0xffff0000u));
        uint l1_ = pack2(yv[4 * mt + 2] - __uint_as_float((h1_ & 0xffffu) << 16),
                         yv[4 * mt + 3] - __uint_as_float(h1_ & 0xffff0000u));
        const int so = pp * 72 + mt * 16 + l4 * 4;
        *(uint2*)&ahiP[so] = make_uint2(h0_, h1_);
        *(uint2*)&aloP[so] = make_uint2(l0_, l1_);
    }
    wstore64(fo2, whiP, wloP, tid);
    __syncthreads();

    // ---- P6c: conv2 MFMA + store ----
    f32x4 z6[4];
    gemm64(whiP, wloP, ahiP, aloP, bvP + 192, lm, l4, pp, z6);

    if (pp < 49) {
        const int py6 = div7s(pp), px6 = pp - py6 * 7;
        const int hwi6 = (ty * 7 + py6) * W + tx * 7 + px6;
#pragma unroll
        for (int mt = 0; mt < 4; ++mt)
#pragma unroll
            for (int r = 0; r < 4; ++r)
                out[(size_t)(b * 64 + mt * 16 + l4 * 4 + r) * HW + hwi6] = z6[mt][r];
    }
}

extern "C" void kernel_launch(void* const* d_in, const int* in_sizes, int n_in,
                              void* d_out, int out_size, void* d_ws, size_t ws_size,
                              hipStream_t stream)
{
    const float* spatial  = (const float*)d_in[0];
    const float* semantic = (const float*)d_in[1];
    const float* rp_w1 = (const float*)d_in[2];
    const float* rp_b1 = (const float*)d_in[3];
    const float* rp_g  = (const float*)d_in[4];
    const float* rp_be = (const float*)d_in[5];
    const float* rp_w2 = (const float*)d_in[6];
    const float* rp_b2 = (const float*)d_in[7];
    const float* fx_w1 = (const float*)d_in[8];
    const float* fx_b1 = (const float*)d_in[9];
    const float* fx_g  = (const float*)d_in[10];
    const float* fx_be = (const float*)d_in[11];
    const float* fx_w2 = (const float*)d_in[12];
    const float* fx_b2 = (const float*)d_in[13];
    const float* op_w1 = (const float*)d_in[14];
    const float* op_b1 = (const float*)d_in[15];
    const float* op_g  = (const float*)d_in[16];
    const float* op_be = (const float*)d_in[17];
    const float* op_w2 = (const float*)d_in[18];
    const float* op_b2 = (const float*)d_in[19];
    const float* sigma = (const float*)d_in[20];

    ushort* px16  = (ushort*)d_ws;                              // 3.21 MB
    float* sqnorm = (float*)((char*)d_ws + (size_t)NPIX * 64 * 2);

    k1_range_proj<<<NBLK, 256, 0, stream>>>(
        semantic, rp_w1, rp_b1, rp_g, rp_be, rp_w2, rp_b2, px16, sqnorm);
    k23_fused<<<NBLK, 256, 0, stream>>>(
        px16, sqnorm, semantic, spatial,
        fx_w1, fx_b1, fx_g, fx_be, fx_w2, fx_b2,
        op_w1, op_b1, op_g, op_be, op_w2, op_b2,
        sigma, (float*)d_out);
}

// Round 14
// 139.815 us; speedup vs baseline: 1.0137x; 1.0137x over previous
//
#include <hip/hip_runtime.h>

typedef unsigned short ushort;
typedef unsigned int uint;

constexpr int B = 2, C = 64, H = 112, W = 112;
constexpr int HW = H * W;          // 12544
constexpr int NPIX = B * HW;       // 25088
constexpr int NBLK = 512;          // 2 images x 16x16 tiles of 7x7 -> exactly 2 blocks/CU
constexpr float EPS_LN = 1e-6f, EPS_NORM = 1e-7f;

typedef __attribute__((ext_vector_type(8))) short bf16x8;   // 8 bf16 = 4 VGPRs
typedef __attribute__((ext_vector_type(4))) float f32x4;

__device__ __forceinline__ float rcp_fast(float x) { return __builtin_amdgcn_rcpf(x); }
__device__ __forceinline__ float sigmoid_f(float x) { return rcp_fast(1.f + __expf(-x)); }
__device__ __forceinline__ int uni(int x) { return __builtin_amdgcn_readfirstlane(x); }
__device__ __forceinline__ int div7s(int x)  { return (x * 9363) >> 16; }   // exact for 0<=x<64
__device__ __forceinline__ int div13s(int x) { return (x * 5042) >> 16; }   // exact for 0<=x<169

// f32 -> bf16 bits (round-nearest-even) + pair pack/unpack.
__device__ __forceinline__ ushort rne16(float x) {
    uint u = __float_as_uint(x);
    u += 0x7fffu + ((u >> 16) & 1u);
    return (ushort)(u >> 16);
}
__device__ __forceinline__ uint pack2(float a, float b) {
    return (uint)rne16(a) | ((uint)rne16(b) << 16);
}
__device__ __forceinline__ float2 up2(uint u) {
    return make_float2(__uint_as_float(u << 16), __uint_as_float(u & 0xffff0000u));
}
__device__ __forceinline__ float up1(ushort u) {
    return __uint_as_float((uint)u << 16);
}

__device__ __forceinline__ f32x4 mfma16(bf16x8 a, bf16x8 b, f32x4 c) {
    return __builtin_amdgcn_mfma_f32_16x16x32_bf16(a, b, c, 0, 0, 0);
}

// XCD-patch swizzle (BOTH kernels -> producer/consumer share an XCD L2).
__device__ __forceinline__ void decode_blk(int blk, int& b, int& ty, int& tx) {
    int p8 = blk & 7, i = blk >> 3;          // i in [0,64)
    b = p8 >> 2;
    int quad = p8 & 3;
    int lty = i >> 3, ltx = i & 7;           // 8x8 tiles per quadrant
    ty = (quad >> 1) * 8 + lty;              // [0,16)
    tx = (quad & 1) * 8 + ltx;
}

// ---------------------------------------------------------------------------
// Split-bf16 GEMM helpers. Weights/activations [64 rows][72] bf16 hi/lo.
// ---------------------------------------------------------------------------
__device__ __forceinline__ void stage_w(const float* __restrict__ wsrc,
                                        ushort* wh, ushort* wl, int tid)
{
#pragma unroll
    for (int i = 0; i < 8; ++i) {
        int idx2 = i * 256 + tid;            // 2048 float pairs = 64x64
        int o = idx2 >> 5, k = (idx2 & 31) * 2;
        float2 xy = *(const float2*)&wsrc[o * 64 + k];
        uint h = pack2(xy.x, xy.y);
        *(uint*)&wh[o * 72 + k] = h;
        *(uint*)&wl[o * 72 + k] = pack2(xy.x - __uint_as_float((h & 0xffffu) << 16),
                                        xy.y - __uint_as_float(h & 0xffff0000u));
    }
}

// Stage a nrow x ncol (<=64x64) matrix with arbitrary row stride into the
// zero-padded [64][72] hi/lo strips. thread t: row t>>2, col quarter t&3.
__device__ __forceinline__ void stage_wpad(const float* __restrict__ src, int ld,
                                           int nrow, int ncol,
                                           ushort* wh, ushort* wl, int tid)
{
    const int o = tid >> 2, q = (tid & 3) * 16;
#pragma unroll
    for (int jj = 0; jj < 8; ++jj) {
        int c = q + 2 * jj;
        float x0 = (o < nrow && c < ncol)     ? src[o * ld + c]     : 0.f;
        float x1 = (o < nrow && c + 1 < ncol) ? src[o * ld + c + 1] : 0.f;
        uint hh = pack2(x0, x1);
        uint ll = pack2(x0 - __uint_as_float((hh & 0xffffu) << 16),
                        x1 - __uint_as_float(hh & 0xffff0000u));
        *(uint*)&wh[o * 72 + c] = hh;
        *(uint*)&wl[o * 72 + c] = ll;
    }
}

__device__ __forceinline__ void gemm64_acc(const ushort* __restrict__ wh, const ushort* __restrict__ wl,
                                           const ushort* __restrict__ xh, const ushort* __restrict__ xl,
                                           int lm, int l4, int pp, f32x4 acc[4])
{
#pragma unroll
    for (int kt = 0; kt < 2; ++kt) {
        const int xo = pp * 72 + kt * 32 + l4 * 8;
        bf16x8 bh = *(const bf16x8*)&xh[xo];
        bf16x8 bl = *(const bf16x8*)&xl[xo];
#pragma unroll
        for (int mt = 0; mt < 4; ++mt) {
            const int wo = (mt * 16 + lm) * 72 + kt * 32 + l4 * 8;
            bf16x8 ah = *(const bf16x8*)&wh[wo];
            bf16x8 al = *(const bf16x8*)&wl[wo];
            acc[mt] = mfma16(al, bh, acc[mt]);
            acc[mt] = mfma16(ah, bl, acc[mt]);
            acc[mt] = mfma16(ah, bh, acc[mt]);
        }
    }
}

__device__ __forceinline__ void gemm64(const ushort* __restrict__ wh, const ushort* __restrict__ wl,
                                       const ushort* __restrict__ xh, const ushort* __restrict__ xl,
                                       const float* __restrict__ bias,
                                       int lm, int l4, int pp, f32x4 acc[4])
{
#pragma unroll
    for (int mt = 0; mt < 4; ++mt) {
        const int ob = mt * 16 + l4 * 4;
        acc[mt][0] = bias[ob]; acc[mt][1] = bias[ob + 1];
        acc[mt][2] = bias[ob + 2]; acc[mt][3] = bias[ob + 3];
    }
    gemm64_acc(wh, wl, xh, xl, lm, l4, pp, acc);
}

// ---------------------------------------------------------------------------
// k1: px = range_proj(semantic) -> px16[p][64] (bf16) + sqnorm[p].
// Unchanged from r7 (full split-bf16 MFMA; verified; ~7 us).
// ---------------------------------------------------------------------------
__global__ __launch_bounds__(256) void k1_range_proj(
    const float* __restrict__ sem,
    const float* __restrict__ w1, const float* __restrict__ b1,
    const float* __restrict__ g,  const float* __restrict__ be,
    const float* __restrict__ w2, const float* __restrict__ b2,
    ushort* __restrict__ px16, float* __restrict__ sqnorm)
{
    __shared__ __align__(16) ushort u16[28160];   // 56320 B
    ushort* wh1 = u16;                 // [64][72] each (4608 ushorts)
    ushort* wl1 = u16 + 4608;
    ushort* wh2 = u16 + 9216;
    ushort* wl2 = u16 + 13824;
    ushort* xh  = u16 + 18432;         // activations / s (reused)
    ushort* xl  = u16 + 23040;         // ..27648
    float*  bv  = (float*)(u16 + 27648);   // b1|g|be|b2 (256 floats)

    const int tid = threadIdx.x, lane = tid & 63, wv = tid >> 6;
    const int lm = lane & 15, l4 = lane >> 4;
    int b, ty, tx; decode_blk(blockIdx.x, b, ty, tx);

    {
        const int lp = lane < 49 ? lane : 48;
        const int py = div7s(lp), px = lp - py * 7;
        const int hw = (ty * 7 + py) * W + tx * 7 + px;
        const bool a = lane < 49;
        float xv[16];
#pragma unroll
        for (int j = 0; j < 16; ++j)
            xv[j] = a ? sem[(size_t)(b * 64 + wv * 16 + j) * HW + hw] : 0.f;
        uint hu[8], lu[8];
#pragma unroll
        for (int jj = 0; jj < 8; ++jj) {
            uint hh = pack2(xv[2 * jj], xv[2 * jj + 1]);
            hu[jj] = hh;
            lu[jj] = pack2(xv[2 * jj]     - __uint_as_float((hh & 0xffffu) << 16),
                           xv[2 * jj + 1] - __uint_as_float(hh & 0xffff0000u));
        }
        const int rb = lane * 72 + wv * 16;
        *(uint4*)&xh[rb]     = make_uint4(hu[0], hu[1], hu[2], hu[3]);
        *(uint4*)&xh[rb + 8] = make_uint4(hu[4], hu[5], hu[6], hu[7]);
        *(uint4*)&xl[rb]     = make_uint4(lu[0], lu[1], lu[2], lu[3]);
        *(uint4*)&xl[rb + 8] = make_uint4(lu[4], lu[5], lu[6], lu[7]);
    }
    stage_w(w1, wh1, wl1, tid);
    stage_w(w2, wh2, wl2, tid);
    if (tid < 64) { bv[tid] = b1[tid]; bv[64 + tid] = g[tid];
                    bv[128 + tid] = be[tid]; bv[192 + tid] = b2[tid]; }
    __syncthreads();

    const int pp = wv * 16 + lm;
    f32x4 f[4];
    gemm64(wh1, wl1, xh, xl, bv, lm, l4, pp, f);

    float psum = 0.f, psq = 0.f;
#pragma unroll
    for (int mt = 0; mt < 4; ++mt)
#pragma unroll
        for (int r = 0; r < 4; ++r) { float fv = f[mt][r]; psum += fv; psq += fv * fv; }
    psum += __shfl_xor(psum, 16); psum += __shfl_xor(psum, 32);
    psq  += __shfl_xor(psq, 16);  psq  += __shfl_xor(psq, 32);
    const float m = psum * (1.f / 64.f);
    const float rstd = rsqrtf(psq * (1.f / 64.f) - m * m + EPS_LN);

    float sv_[16];
#pragma unroll
    for (int mt = 0; mt < 4; ++mt)
#pragma unroll
        for (int r = 0; r < 4; ++r) {
            const int o = mt * 16 + l4 * 4 + r;
            float y = bv[64 + o] * (f[mt][r] - m) * rstd + bv[128 + o];
            sv_[mt * 4 + r] = y * sigmoid_f(y);
        }
    __syncthreads();
#pragma unroll
    for (int mt = 0; mt < 4; ++mt) {
        uint h0 = pack2(sv_[4 * mt],     sv_[4 * mt + 1]);
        uint h1 = pack2(sv_[4 * mt + 2], sv_[4 * mt + 3]);
        uint l0 = pack2(sv_[4 * mt]     - __uint_as_float((h0 & 0xffffu) << 16),
                        sv_[4 * mt + 1] - __uint_as_float(h0 & 0xffff0000u));
        uint l1 = pack2(sv_[4 * mt + 2] - __uint_as_float((h1 & 0xffffu) << 16),
                        sv_[4 * mt + 3] - __uint_as_float(h1 & 0xffff0000u));
        const int so = pp * 72 + mt * 16 + l4 * 4;
        *(uint2*)&xh[so] = make_uint2(h0, h1);
        *(uint2*)&xl[so] = make_uint2(l0, l1);
    }
    __syncthreads();

    f32x4 z[4];
    gemm64(wh2, wl2, xh, xl, bv + 192, lm, l4, pp, z);

    float sq = 0.f;
#pragma unroll
    for (int mt = 0; mt < 4; ++mt)
#pragma unroll
        for (int r = 0; r < 4; ++r) sq += z[mt][r] * z[mt][r];
    sq += __shfl_xor(sq, 16); sq += __shfl_xor(sq, 32);

    if (pp < 49) {
        const int py = div7s(pp), px = pp - py * 7;
        const int hwi = (ty * 7 + py) * W + tx * 7 + px;
        ushort* dst = &px16[((size_t)b * HW + hwi) * 64];
#pragma unroll
        for (int mt = 0; mt < 4; ++mt)
            *(uint2*)&dst[mt * 16 + l4 * 4] =
                make_uint2(pack2(z[mt][0], z[mt][1]), pack2(z[mt][2], z[mt][3]));
        if (l4 == 0) sqnorm[(size_t)b * HW + hwi] = sq;
    }
}

// ---------------------------------------------------------------------------
// k23 (r14 = r12, best verified): P2/P3/P6 MFMA; dmat bf16; haloB staged at
// entry; division-free P5. r13's T14 async-split was null -> reverted.
// ---------------------------------------------------------------------------
__global__ __launch_bounds__(256, 2) void k23_fused(
    const ushort* __restrict__ px16, const float* __restrict__ sqnorm,
    const float* __restrict__ sem,  const float* __restrict__ spat,
    const float* __restrict__ fw1, const float* __restrict__ fb1,
    const float* __restrict__ fg,  const float* __restrict__ fbe,
    const float* __restrict__ fw2, const float* __restrict__ fb2,
    const float* __restrict__ w1, const float* __restrict__ b1,
    const float* __restrict__ g,  const float* __restrict__ be,
    const float* __restrict__ w2, const float* __restrict__ b2,
    const float* __restrict__ sigma_, float* __restrict__ out)
{
    __shared__ __align__(16) float smem[18048];          // 72192 B arena
    // Phase A:
    ushort* haloA  = (ushort*)smem;                      // [169][64] bf16 fl [0,5408)
    ushort* dmat16 = (ushort*)(smem + 5408);             // [176][66] bf16 fl [5408,11216)
    float*  sqn_l  = smem + 11216;                       // 169 fl [11216,11385)
    ushort* haloB  = (ushort*)(smem + 12640);            // [169][64] bf16 fl [12640,18048) — staged at ENTRY
    // post-extraction overlays (haloA/dmat16/sqn dead):
    float*  comb  = smem;                                // 3136 fl [0,3136)
    float*  bv3   = smem + 3136;                         // 256: fb1|fb2|fg|fbe
    float*  pt    = smem + 3136;                         // 64 (overlays dead fb1)
    ushort* Xh    = (ushort*)(smem + 3392);              // [64][72] fl [3392,5696)
    ushort* Xl    = (ushort*)(smem + 5696);              // fl [5696,8000)
    ushort* Ah    = (ushort*)(smem + 8000);              // fl [8000,10304)
    ushort* Al    = (ushort*)(smem + 10304);             // fl [10304,12608)
    // P5/P6 overlays:
    float*  bvP   = smem + 3136;                         // 256 (pt/bv3 dead)
    ushort* whiP  = (ushort*)(smem + 8000);              // over A strip
    ushort* wloP  = (ushort*)(smem + 10304);
    ushort* ahiP  = (ushort*)(smem + 3392);              // over X strip
    ushort* aloP  = (ushort*)(smem + 5696);

    const int tid = threadIdx.x, lane = tid & 63, wv = tid >> 6;
    const int lm = lane & 15, l4 = lane >> 4;
    int b, ty, tx; decode_blk(blockIdx.x, b, ty, tx);
    const int lp  = lane < 49 ? lane : 48;
    const int py  = div7s(lp), pxl = lp - py * 7;
    const int h = ty * 7 + py, w = tx * 7 + pxl;
    const int hw = h * W + w;
    const int h0 = ty * 7 - 3, w0 = tx * 7 - 3;
    const bool act = lane < 49;
    const int pp = wv * 16 + lm;

    // ---- sv16 prefetch: this thread's 16-channel slice (X2 staging) ----
    float sv16[16];
#pragma unroll
    for (int j = 0; j < 16; ++j)
        sv16[j] = sem[(size_t)(b * 64 + wv * 16 + j) * HW + hw];

    // ---- haloB staging at ENTRY: latency hides under P1+P2+extraction ----
    if (tid < 169) {
        const int ry = div13s(tid), rx = tid - ry * 13;
        const int hh = h0 + ry, ww = w0 + rx;
        const bool valid = (unsigned)hh < (unsigned)H && (unsigned)ww < (unsigned)W;
        const int soff = hh * W + ww;
        const int rsw = (tid & 7), rb_ = tid << 6;
#pragma unroll
        for (int cq = 0; cq < 8; ++cq) {
            uint4 v = make_uint4(0u, 0u, 0u, 0u);
            if (valid) {
                const float* sp = &spat[(size_t)(b * 64 + 8 * cq) * HW + soff];
                v.x = pack2(sp[0],      sp[HW]);
                v.y = pack2(sp[2 * HW], sp[3 * HW]);
                v.z = pack2(sp[4 * HW], sp[5 * HW]);
                v.w = pack2(sp[6 * HW], sp[7 * HW]);
            }
            *(uint4*)&haloB[rb_ + ((cq ^ rsw) << 3)] = v;
        }
    }

    // ---- P1: stage px halo -> haloA (bf16): 1352 16-B loads ----
    for (int i = 0; i < 6; ++i) {
        int idx = i * 256 + tid;
        if (idx < 1352) {
            int r = idx >> 3, q = idx & 7;
            int ry = div13s(r), rx = r - ry * 13;
            int hh = h0 + ry, ww = w0 + rx;
            bool valid = (unsigned)hh < (unsigned)H && (unsigned)ww < (unsigned)W;
            uint4 v = make_uint4(0u, 0u, 0u, 0u);
            if (valid) v = *(const uint4*)&px16[((size_t)b * HW + hh * W + ww) * 64 + 8 * q];
            *(uint4*)&haloA[(r << 6) + ((q ^ (r & 7)) << 3)] = v;
        }
    }
    if (tid < 169) {
        int ry = div13s(tid), rx = tid - ry * 13;
        int hh = h0 + ry, ww = w0 + rx;
        bool valid = (unsigned)hh < (unsigned)H && (unsigned)ww < (unsigned)W;
        float v = 0.f;
        if (valid) v = sqnorm[(size_t)b * HW + hh * W + ww];
        sqn_l[tid] = v;
    }
    __syncthreads();

    // ---- P2-MFMA: D[hp][p] = <haloA[hp], haloA[rp(p)]> -> dmat16 (bf16) ----
    {
        const int qp = pp < 49 ? pp : 48;
        const int pyp = div7s(qp), pxp = qp - pyp * 7;
        const int rpp = pyp * 13 + pxp + 42;
        bf16x8 bc0 = *(const bf16x8*)&haloA[(rpp << 6) + ((l4 ^ (rpp & 7)) << 3)];
        bf16x8 bc1 = *(const bf16x8*)&haloA[(rpp << 6) + (((4 + l4) ^ (rpp & 7)) << 3)];
#pragma unroll
        for (int mt = 0; mt < 11; ++mt) {
            const int r = mt * 16 + lm;
            bf16x8 a0 = *(const bf16x8*)&haloA[(r << 6) + ((l4 ^ (r & 7)) << 3)];
            bf16x8 a1 = *(const bf16x8*)&haloA[(r << 6) + (((4 + l4) ^ (r & 7)) << 3)];
            f32x4 d = {0.f, 0.f, 0.f, 0.f};
            d = mfma16(a0, bc0, d);
            d = mfma16(a1, bc1, d);
            const int orow = mt * 16 + l4 * 4;
#pragma unroll
            for (int rr = 0; rr < 4; ++rr)
                dmat16[(orow + rr) * 66 + pp] = rne16(d[rr]);
        }
    }
    __syncthreads();

    // ---- extraction (wave-split n) into regs ----
    const int rbase = py * 13 + pxl;
    const int rp = rbase + 42;
    float cbl[13];
    {
        const float sqc = sqn_l[rp];
        const float sg_ = sigma_[0];
        const float inv2s2 = rcp_fast(2.f * sg_ * sg_);
#pragma unroll
        for (int i = 0; i < 13; ++i) {
            const int n = uni(wv + 4 * i);
            cbl[i] = 0.f;
            if (n < 49) {
                int ryn = div7s(n), rxn = n - ryn * 7;
                int dy = ryn - 3, dx = rxn - 3;
                int rn = rbase + ryn * 13 + rxn;
                float dot = up1(dmat16[rn * 66 + lane]);
                float dist2 = fmaxf(sqn_l[rn] + sqc - 2.f * dot, 0.f);
                bool validn = (unsigned)(h + dy) < (unsigned)H && (unsigned)(w + dx) < (unsigned)W;
                float d2n = (float)(dy * dy + dx * dx);
                cbl[i] = validn ? __expf(-(dist2 * (1.f / 128.f) + d2n * inv2s2)) : 0.f;
            }
        }
    }
    __syncthreads();   // dmat16/haloA/sqn dead below

    // ---- post-extraction staging: comb f32 + X1(comb bf16) + A1 + bv3 ----
#pragma unroll
    for (int i = 0; i < 13; ++i) {
        const int n = wv + 4 * i;
        if (n < 49) {
            float v = cbl[i];
            comb[n * 64 + lane] = v;
            ushort hh = rne16(v);
            Xh[lane * 72 + n] = hh;
            Xl[lane * 72 + n] = rne16(v - up1(hh));
        }
    }
    if (tid < 64) {
#pragma unroll
        for (int r = 49; r < 64; ++r) { Xh[tid * 72 + r] = 0; Xl[tid * 72 + r] = 0; }
        bv3[tid]       = (tid < 49) ? fb1[tid] : 0.f;
        bv3[64 + tid]  = (tid < 49) ? fb2[tid] : 0.f;
        bv3[128 + tid] = (tid < 49) ? fg[tid]  : 0.f;
        bv3[192 + tid] = (tid < 49) ? fbe[tid] : 0.f;
    }
    stage_wpad(fw1, 113, 49, 49, Ah, Al, tid);   // A1 = comb-half of fx_w1
    __syncthreads();

    // ---- P3-MFMA: conv1 = A1*X1 + A2*X2, conv2 = A3*X3 ----
    f32x4 accF[4];
    gemm64(Ah, Al, Xh, Xl, bv3, lm, l4, pp, accF);   // bias fb1 + comb part
    __syncthreads();                                  // A1/X1 reads done

    // X2 = sem (from sv16), A2 = sem-half of fx_w1
    {
        uint hu[8], lu[8];
#pragma unroll
        for (int jj = 0; jj < 8; ++jj) {
            float x0 = sv16[2 * jj], x1 = sv16[2 * jj + 1];
            uint hh = pack2(x0, x1);
            hu[jj] = hh;
            lu[jj] = pack2(x0 - __uint_as_float((hh & 0xffffu) << 16),
                           x1 - __uint_as_float(hh & 0xffff0000u));
        }
        const int rb = lane * 72 + wv * 16;
        *(uint4*)&Xh[rb]     = make_uint4(hu[0], hu[1], hu[2], hu[3]);
        *(uint4*)&Xh[rb + 8] = make_uint4(hu[4], hu[5], hu[6], hu[7]);
        *(uint4*)&Xl[rb]     = make_uint4(lu[0], lu[1], lu[2], lu[3]);
        *(uint4*)&Xl[rb + 8] = make_uint4(lu[4], lu[5], lu[6], lu[7]);
    }
    stage_wpad(fw1 + 49, 113, 49, 64, Ah, Al, tid);
    __syncthreads();

    gemm64_acc(Ah, Al, Xh, Xl, lm, l4, pp, accF);    // += sem part

    // LN over o<49 (shfl across l4-groups) + SiLU -> s in regs
    float sarr[16];
    {
        float psum = 0.f, psq = 0.f;
#pragma unroll
        for (int mt = 0; mt < 4; ++mt)
#pragma unroll
            for (int r = 0; r < 4; ++r) {
                const int o = mt * 16 + l4 * 4 + r;
                if (o < 49) { float fv = accF[mt][r]; psum += fv; psq += fv * fv; }
            }
        psum += __shfl_xor(psum, 16); psum += __shfl_xor(psum, 32);
        psq  += __shfl_xor(psq, 16);  psq  += __shfl_xor(psq, 32);
        const float m = psum * (1.f / 49.f);
        const float rstd = rsqrtf(psq * (1.f / 49.f) - m * m + EPS_LN);
#pragma unroll
        for (int mt = 0; mt < 4; ++mt)
#pragma unroll
            for (int r = 0; r < 4; ++r) {
                const int o = mt * 16 + l4 * 4 + r;
                float s = 0.f;
                if (o < 49) {
                    float y = bv3[128 + o] * (accF[mt][r] - m) * rstd + bv3[192 + o];
                    s = y * sigmoid_f(y);
                }
                sarr[mt * 4 + r] = s;
            }
    }
    __syncthreads();                                  // A2/X2 reads done

    // X3 = s (rows o, col pp), A3 = fx_w2
#pragma unroll
    for (int mt = 0; mt < 4; ++mt) {
        uint h0_ = pack2(sarr[4 * mt],     sarr[4 * mt + 1]);
        uint h1_ = pack2(sarr[4 * mt + 2], sarr[4 * mt + 3]);
        uint l0_ = pack2(sarr[4 * mt]     - __uint_as_float((h0_ & 0xffffu) << 16),
                         sarr[4 * mt + 1] - __uint_as_float(h0_ & 0xffff0000u));
        uint l1_ = pack2(sarr[4 * mt + 2] - __uint_as_float((h1_ & 0xffffu) << 16),
                         sarr[4 * mt + 3] - __uint_as_float(h1_ & 0xffff0000u));
        const int so = pp * 72 + mt * 16 + l4 * 4;
        *(uint2*)&Xh[so] = make_uint2(h0_, h1_);
        *(uint2*)&Xl[so] = make_uint2(l0_, l1_);
    }
    stage_wpad(fw2, 49, 49, 49, Ah, Al, tid);
    __syncthreads();

    f32x4 accG[4];
    gemm64(Ah, Al, Xh, Xl, bv3 + 64, lm, l4, pp, accG);   // bias fb2

    // gate + comb update + column sums -> pt[pp]
    {
        float tacc = 0.f;
#pragma unroll
        for (int mt = 0; mt < 4; ++mt)
#pragma unroll
            for (int r = 0; r < 4; ++r) {
                const int o = mt * 16 + l4 * 4 + r;
                if (o < 49) {
                    float gate = 1.f + sigmoid_f(accG[mt][r]);
                    float cx = comb[o * 64 + pp] * gate;   // unique (o,pp) per lane
                    comb[o * 64 + pp] = cx;
                    tacc += cx;
                }
            }
        tacc += __shfl_xor(tacc, 16); tacc += __shfl_xor(tacc, 32);
        if (l4 == 0) pt[pp] = tacc;
    }
    __syncthreads();
    const float inv = rcp_fast(pt[lane] + EPS_NORM);
    __syncthreads();   // all pt reads done -> bvP overlay safe

    // ---- stage op_w1 (over dead A strip) + bias vec; hides under P5 ----
    stage_w(w1, whiP, wloP, tid);
    if (tid < 64) { bvP[tid] = b1[tid]; bvP[64 + tid] = g[tid];
                    bvP[128 + tid] = be[tid]; bvP[192 + tid] = b2[tid]; }

    // ---- P5: weighted neighborhood reduction (haloB, staged at entry) ----
    const int c0 = uni(wv * 16);
    const int qq0 = c0 >> 3;
    float acc[16];
#pragma unroll
    for (int j = 0; j < 16; ++j) acc[j] = 0.f;
    for (int ryn = 0; ryn < 7; ++ryn) {
#pragma unroll
        for (int rxn = 0; rxn < 7; ++rxn) {
            const int n = ryn * 7 + rxn;
            const int rn = rbase + ryn * 13 + rxn;
            float cn = comb[n * 64 + lane] * inv;
            const int rb_ = rn << 6, rsw = rn & 7;
#pragma unroll
            for (int q = 0; q < 2; ++q) {
                uint4 v = *(const uint4*)&haloB[rb_ + (((qq0 + q) ^ rsw) << 3)];
                float2 a = up2(v.x), bb = up2(v.y), c = up2(v.z), d = up2(v.w);
                acc[8 * q + 0] += cn * a.x;  acc[8 * q + 1] += cn * a.y;
                acc[8 * q + 2] += cn * bb.x; acc[8 * q + 3] += cn * bb.y;
                acc[8 * q + 4] += cn * c.x;  acc[8 * q + 5] += cn * c.y;
                acc[8 * q + 6] += cn * d.x;  acc[8 * q + 7] += cn * d.y;
            }
        }
    }
    __syncthreads();   // comb/haloB reads done; whiP/bvP staging visible

    // ---- P6a: write P5 result as split-bf16 activations [pixel][72] ----
    {
        uint hu[8], lu[8];
#pragma unroll
        for (int jj = 0; jj < 8; ++jj) {
            float x0 = act ? acc[2 * jj] : 0.f;
            float x1 = act ? acc[2 * jj + 1] : 0.f;
            uint hh = pack2(x0, x1);
            hu[jj] = hh;
            lu[jj] = pack2(x0 - __uint_as_float((hh & 0xffffu) << 16),
                           x1 - __uint_as_float(hh & 0xffff0000u));
        }
        const int rb = lane * 72 + c0;
        *(uint4*)&ahiP[rb]     = make_uint4(hu[0], hu[1], hu[2], hu[3]);
        *(uint4*)&ahiP[rb + 8] = make_uint4(hu[4], hu[5], hu[6], hu[7]);
        *(uint4*)&aloP[rb]     = make_uint4(lu[0], lu[1], lu[2], lu[3]);
        *(uint4*)&aloP[rb + 8] = make_uint4(lu[4], lu[5], lu[6], lu[7]);
    }
    __syncthreads();

    // ---- P6b: conv1 MFMA + LN(shfl) ----
    f32x4 f6[4];
    gemm64(whiP, wloP, ahiP, aloP, bvP, lm, l4, pp, f6);

    float psum = 0.f, psq = 0.f;
#pragma unroll
    for (int mt = 0; mt < 4; ++mt)
#pragma unroll
        for (int r = 0; r < 4; ++r) { float fv = f6[mt][r]; psum += fv; psq += fv * fv; }
    psum += __shfl_xor(psum, 16); psum += __shfl_xor(psum, 32);
    psq  += __shfl_xor(psq, 16);  psq  += __shfl_xor(psq, 32);
    const float m6 = psum * (1.f / 64.f);
    const float rstd6 = rsqrtf(psq * (1.f / 64.f) - m6 * m6 + EPS_LN);

    float yv[16];
#pragma unroll
    for (int mt = 0; mt < 4; ++mt)
#pragma unroll
        for (int r = 0; r < 4; ++r) {
            const int o = mt * 16 + l4 * 4 + r;
            yv[mt * 4 + r] = bvP[64 + o] * (f6[mt][r] - m6) * rstd6 + bvP[128 + o];
        }
    __syncthreads();   // conv1 fragment reads done -> strips reusable

    // write y (split bf16) over act strip; restage op_w2 over W strip
#pragma unroll
    for (int mt = 0; mt < 4; ++mt) {
        uint h0_ = pack2(yv[4 * mt],     yv[4 * mt + 1]);
        uint h1_ = pack2(yv[4 * mt + 2], yv[4 * mt + 3]);
        uint l0_ = pack2(yv[4 * mt]     - __uint_as_float((h0_ & 0xffffu) << 16),
                         yv[4 * mt + 1] - __uint_as_float(h0_ & 0xffff0000u));
        uint l1_ = pack2(yv[4 * mt + 2] - __uint_as_float((h1_ & 0xffffu) << 16),
                         yv[4 * mt + 3] - __uint_as_float(h1_ & 0xffff0000u));
        const int so = pp * 72 + mt * 16 + l4 * 4;
        *(uint2*)&ahiP[so] = make_uint2(h0_, h1_);
        *(uint2*)&aloP[so] = make_uint2(l0_, l1_);
    }
    stage_w(w2, whiP, wloP, tid);
    __syncthreads();

    // ---- P6c: conv2 MFMA + store ----
    f32x4 z6[4];
    gemm64(whiP, wloP, ahiP, aloP, bvP + 192, lm, l4, pp, z6);

    if (pp < 49) {
        const int py6 = div7s(pp), px6 = pp - py6 * 7;
        const int hwi6 = (ty * 7 + py6) * W + tx * 7 + px6;
#pragma unroll
        for (int mt = 0; mt < 4; ++mt)
#pragma unroll
            for (int r = 0; r < 4; ++r)
                out[(size_t)(b * 64 + mt * 16 + l4 * 4 + r) * HW + hwi6] = z6[mt][r];
    }
}

extern "C" void kernel_launch(void* const* d_in, const int* in_sizes, int n_in,
                              void* d_out, int out_size, void* d_ws, size_t ws_size,
                              hipStream_t stream)
{
    const float* spatial  = (const float*)d_in[0];
    const float* semantic = (const float*)d_in[1];
    const float* rp_w1 = (const float*)d_in[2];
    const float* rp_b1 = (const float*)d_in[3];
    const float* rp_g  = (const float*)d_in[4];
    const float* rp_be = (const float*)d_in[5];
    const float* rp_w2 = (const float*)d_in[6];
    const float* rp_b2 = (const float*)d_in[7];
    const float* fx_w1 = (const float*)d_in[8];
    const float* fx_b1 = (const float*)d_in[9];
    const float* fx_g  = (const float*)d_in[10];
    const float* fx_be = (const float*)d_in[11];
    const float* fx_w2 = (const float*)d_in[12];
    const float* fx_b2 = (const float*)d_in[13];
    const float* op_w1 = (const float*)d_in[14];
    const float* op_b1 = (const float*)d_in[15];
    const float* op_g  = (const float*)d_in[16];
    const float* op_be = (const float*)d_in[17];
    const float* op_w2 = (const float*)d_in[18];
    const float* op_b2 = (const float*)d_in[19];
    const float* sigma = (const float*)d_in[20];

    ushort* px16  = (ushort*)d_ws;                              // 3.21 MB
    float* sqnorm = (float*)((char*)d_ws + (size_t)NPIX * 64 * 2);

    k1_range_proj<<<NBLK, 256, 0, stream>>>(
        semantic, rp_w1, rp_b1, rp_g, rp_be, rp_w2, rp_b2, px16, sqnorm);
    k23_fused<<<NBLK, 256, 0, stream>>>(
        px16, sqnorm, semantic, spatial,
        fx_w1, fx_b1, fx_g, fx_be, fx_w2, fx_b2,
        op_w1, op_b1, op_g, op_be, op_w2, op_b2,
        sigma, (float*)d_out);
}